// Round 9
// baseline (1086.137 us; speedup 1.0000x reference)
//
#include <hip/hip_runtime.h>

// Graph_CNN_ortega — pure-bf16 MFMA. Big GEMMs: 256x128 tile, BK=32, A via
// ring-3 global_load_lds (48KB LDS), B streamed DIRECTLY global->VGPR with
// register double-buffer (skips LDS for B: 88->48 KB LDS traffic per tile,
// the measured invariant ~800TF ceiling was LDS-BW). MLP1+MLP2 fused.
// B=64, N=1024, DIN=64, DH=128, H_MLP=128, L=3, C=4.

typedef unsigned short u16;
typedef short bf16x8 __attribute__((ext_vector_type(8)));
typedef float f32x4 __attribute__((ext_vector_type(4)));
typedef u16 u16x4 __attribute__((ext_vector_type(4)));

__device__ __forceinline__ u16 f2bf(float x){
  unsigned u = __builtin_bit_cast(unsigned, x);
  u += 0x7fffu + ((u >> 16) & 1u);          // RNE
  return (u16)(u >> 16);
}
__device__ __forceinline__ float bf2f(u16 h){
  return __builtin_bit_cast(float, ((unsigned)h) << 16);
}
__device__ __forceinline__ void gload16(const u16* g, u16* l){
  __builtin_amdgcn_global_load_lds(
      (const __attribute__((address_space(1))) unsigned int*)(g),
      (__attribute__((address_space(3))) unsigned int*)(l), 16, 0, 0);
}

// ---------------- preprocessing ----------------

__global__ void prep_weights(const float* __restrict__ w1_0, const float* __restrict__ w2_0,
                             const float* __restrict__ w1_r, const float* __restrict__ w2_r,
                             const float* __restrict__ bw,
                             u16* __restrict__ W1T0, u16* __restrict__ W2T0,
                             u16* __restrict__ W1Tr, u16* __restrict__ W2Tr,
                             float* __restrict__ wsb){
  int id = blockIdx.x*256 + threadIdx.x;
  if (id < 3){
    float a0=bw[id*3+0], a1=bw[id*3+1], a2=bw[id*3+2];
    float m = fmaxf(a0,fmaxf(a1,a2));
    float e0=expf(a0-m), e1=expf(a1-m), e2=expf(a2-m);
    float s = e0+e1+e2;
    wsb[id*3+0]=e0/s; wsb[id*3+1]=e1/s; wsb[id*3+2]=e2/s;
  }
  if (id < 24576){                       // W1T0[k][h][d]=w1_0[k][d][h], d<64
    int k=id/8192, rem=id%8192, h=rem/64, d=rem%64;
    W1T0[id] = f2bf(w1_0[(k*64+d)*128 + h]);
  } else if (id < 73728){                // W2T0[k][o][h]=w2_0[k][h][o]
    int t=id-24576, k=t/16384, rem=t%16384, o=rem/128, h=rem%128;
    W2T0[t] = f2bf(w2_0[(k*128+h)*128 + o]);
  } else if (id < 172032){               // W1Tr[lk][h][d]=w1_r[lk][d][h]
    int t=id-73728, lk=t/16384, rem=t%16384, h=rem/128, d=rem%128;
    W1Tr[t] = f2bf(w1_r[lk*16384 + d*128 + h]);
  } else if (id < 270336){               // W2Tr[lk][o][h]=w2_r[lk][h][o]
    int t=id-172032, lk=t/16384, rem=t%16384, o=rem/128, h=rem%128;
    W2Tr[t] = f2bf(w2_r[lk*16384 + h*128 + o]);
  }
}

// U[3][1024][1024] f32 -> UTcat[k][i][j]=U[k][j][i] and Ucat[i][k*1024+j]
__global__ void prep_U(const float* __restrict__ U, u16* __restrict__ UTcat,
                       u16* __restrict__ Ucat){
  __shared__ float t[32][33];
  int k = blockIdx.z, i0 = blockIdx.x*32, j0 = blockIdx.y*32;
  size_t kb = (size_t)k << 20;
  #pragma unroll
  for (int rr=0; rr<4; rr++){
    int r = threadIdx.y*4+rr, c = threadIdx.x;
    float v = U[kb + (size_t)(j0+r)*1024 + i0+c];
    t[r][c] = v;
    Ucat[(size_t)(j0+r)*3072 + k*1024 + i0+c] = f2bf(v);
  }
  __syncthreads();
  #pragma unroll
  for (int rr=0; rr<4; rr++){
    int r = threadIdx.y*4+rr, c = threadIdx.x;
    UTcat[kb + (size_t)(i0+r)*1024 + j0+c] = f2bf(t[c][r]);
  }
}

// x[b][j][d] -> HT0[(b*64+d)][j] bf16
__global__ void prep_x(const float* __restrict__ x, u16* __restrict__ H){
  __shared__ float t[32][33];
  int b = blockIdx.z, d0 = blockIdx.x*32, j0 = blockIdx.y*32;
  #pragma unroll
  for (int rr=0;rr<4;rr++){
    int r=threadIdx.y*4+rr, c=threadIdx.x;
    t[r][c] = x[((size_t)b*1024 + j0+r)*64 + d0+c];
  }
  __syncthreads();
  #pragma unroll
  for (int rr=0;rr<4;rr++){
    int r=threadIdx.y*4+rr, c=threadIdx.x;
    H[(size_t)(b*64 + d0+r)*1024 + j0+c] = f2bf(t[c][r]);
  }
}

// ---------------- big NT GEMM: 256x128 tile, BK=32. A: ring-3 gload16->LDS
// (chunk swizzle k^((row>>1)&3), source pre-swizzled, dest linear). B: direct
// global->VGPR fragments, register double-buffered (no LDS). Issue order per
// tile: [B(t+1) x4 global_load] [A-stage(t+2) x2 gload16]; end-of-tile wait
// vmcnt(6) drains A(t+1) (tail: vmcnt(4)); compiler inserts B-use waits.
// REORD=0: C[z*cRowZ + m][n].  REORD=p: col n=(b,d), Din=2^p; writes
// C[((z*64+b)*1024+m)][d] (AGG2 row order (k,b,j)).
template<bool RELU, int REORD>
__global__ __launch_bounds__(512, 4)
void gemm_big(const u16* __restrict__ A, const u16* __restrict__ B,
              u16* __restrict__ C, int Nc, int K, long aZ, int cRowZ)
{
  __shared__ __align__(16) u16 ldsA[3*8192];   // 3 x [256][32]  (48 KB)
  const int tid = threadIdx.x;
  const int z = blockIdx.z;
  const u16* Ab = A + (size_t)z*aZ;
  const int gx = gridDim.x;
  const int nwg = gx*gridDim.y;
  int flat = blockIdx.y*gx + blockIdx.x;
  if ((nwg & 7) == 0) flat = (flat & 7)*(nwg >> 3) + (flat >> 3);  // T1 XCD swizzle
  const int bm = (flat/gx)*256, bn = (flat%gx)*128;
  const int wave = tid>>6, lane = tid&63;
  const int wm = (wave&3)*64, wn = (wave>>2)*64;
  const int rl = lane&15, ksb = lane>>4;
  const int srow = tid>>2;                         // stage row within 128-row round
  const int scol = ((tid&3)*8) ^ (((tid>>3)&3)<<3); // pre-swizzled source col
  const int NT = K>>5;
  // B fragment base: row = bn + wn + ni*16 + rl, k-offset ksb*8
  const u16* Bf = B + (size_t)(bn + wn + rl)*K + ksb*8;

  f32x4 acc[4][4];
  #pragma unroll
  for (int mi=0;mi<4;mi++)
    #pragma unroll
    for (int ni=0;ni<4;ni++){ f32x4 zv={0.f,0.f,0.f,0.f}; acc[mi][ni]=zv; }

  auto stageA = [&](int t){
    const int sa = (t%3)*8192;
    const int k0 = t<<5;
    #pragma unroll
    for (int c=0;c<2;c++)
      gload16(Ab + (size_t)(bm + c*128 + srow)*K + k0 + scol,
              &ldsA[sa + c*4096 + tid*8]);
  };

  bf16x8 bcur[4], bnext[4];
  #pragma unroll
  for (int ni=0;ni<4;ni++)                        // B frags for tile 0
    bcur[ni] = *(const bf16x8*)(Bf + (size_t)(ni*16)*K);
  stageA(0); stageA(1);
  asm volatile("s_waitcnt vmcnt(2)" ::: "memory");   // A(0)+B(0) landed
  __builtin_amdgcn_s_barrier();
  __builtin_amdgcn_sched_barrier(0);

  for (int t=0; t<NT; t++){
    const int sa = (t%3)*8192;
    bf16x8 af[4];
    #pragma unroll
    for (int mi=0;mi<4;mi++){
      const int row = wm + mi*16 + rl;
      af[mi] = *(const bf16x8*)&ldsA[sa + row*32 + ((ksb*8) ^ (((row>>1)&3)<<3))];
    }
    if (t+1 < NT){
      const int k1 = (t+1)<<5;
      #pragma unroll
      for (int ni=0;ni<4;ni++)                    // B frags for tile t+1
        bnext[ni] = *(const bf16x8*)(Bf + (size_t)(ni*16)*K + k1);
    }
    if (t+2 < NT) stageA(t+2);
    __builtin_amdgcn_s_setprio(1);
    #pragma unroll
    for (int ni=0;ni<4;ni++)
      #pragma unroll
      for (int mi=0;mi<4;mi++)
        acc[mi][ni] = __builtin_amdgcn_mfma_f32_16x16x32_bf16(af[mi], bcur[ni], acc[mi][ni], 0,0,0);
    __builtin_amdgcn_s_setprio(0);
    if (t+2 < NT)      asm volatile("s_waitcnt vmcnt(6)" ::: "memory");
    else if (t+1 < NT) asm volatile("s_waitcnt vmcnt(4)" ::: "memory");
    if (t+1 < NT){
      __builtin_amdgcn_s_barrier();
      __builtin_amdgcn_sched_barrier(0);
      #pragma unroll
      for (int ni=0;ni<4;ni++) bcur[ni] = bnext[ni];
    }
  }

  #pragma unroll
  for (int ni=0;ni<4;ni++){
    const int col = bn + wn + ni*16 + rl;
    #pragma unroll
    for (int mi=0;mi<4;mi++){
      const int row0 = bm + wm + mi*16 + ksb*4;          // m89 C layout
      #pragma unroll
      for (int r=0;r<4;r++){
        float v = acc[mi][ni][r];
        if (RELU) v = fmaxf(v, 0.f);
        if constexpr (REORD){
          const int Din = 1 << REORD;
          const int bb = col >> REORD, d = col & (Din-1);
          C[((size_t)((z<<6) + bb)*1024 + row0 + r)*Din + d] = f2bf(v);
        } else {
          C[(size_t)(z*cRowZ + row0 + r)*Nc + col] = f2bf(v);
        }
      }
    }
  }
}

// ---------------- fused MLP: M1 never leaves LDS ----------------
template<int DIN>
__global__ __launch_bounds__(256)
void fused_mlp(const u16* __restrict__ AGG, const u16* __restrict__ W1T,
               const u16* __restrict__ W2T, const float* __restrict__ b1g,
               const float* __restrict__ b2g, const float* __restrict__ wsl,
               u16* __restrict__ M2T)
{
  constexpr int JW1 = 128*DIN;                 // elems of lJ / lW1
  __shared__ __align__(16) u16 lds[2*JW1 + 16384]; // lJ | lW1 | lW2 ; lM1 @0
  const int tid = threadIdx.x;
  const int jt = blockIdx.x, z = blockIdx.z, k = z>>6, b = z&63;
  const u16* Ag  = AGG + ((size_t)z*1024 + jt*128)*DIN;
  const u16* W1k = W1T + k*JW1;
  const u16* W2k = W2T + k*16384;
  const int wave = tid>>6, lane = tid&63;
  const int wm = (wave>>1)*64, wn = (wave&1)*64;
  const int rl = lane&15, ksb = lane>>4;
  const int xr = (rl&7)<<3;

  constexpr int CJ = JW1/2048;                 // gload16s per thread (4 or 8)
  #pragma unroll
  for (int c=0;c<CJ;c++){
    const int e = c*2048 + tid*8, row = e/DIN, col = e%DIN;
    gload16(Ag + (size_t)row*DIN + (col ^ ((row&7)<<3)), &lds[e]);
  }
  #pragma unroll
  for (int c=0;c<CJ;c++){
    const int e = c*2048 + tid*8, row = e/DIN, col = e%DIN;
    gload16(W1k + (size_t)row*DIN + (col ^ ((row&7)<<3)), &lds[JW1 + e]);
  }
  #pragma unroll
  for (int c=0;c<8;c++){
    const int e = c*2048 + tid*8, row = e>>7, col = e&127;
    gload16(W2k + (size_t)row*128 + (col ^ ((row&7)<<3)), &lds[2*JW1 + e]);
  }
  asm volatile("s_waitcnt vmcnt(8)" ::: "memory");   // lJ + lW1 landed
  __builtin_amdgcn_s_barrier();
  __builtin_amdgcn_sched_barrier(0);

  // stage 1: C[j][h] = sum_d AGG[j][d]*W1T[h][d]
  f32x4 acc[4][4];
  #pragma unroll
  for (int mi=0;mi<4;mi++)
    #pragma unroll
    for (int ni=0;ni<4;ni++){ f32x4 zv={0.f,0.f,0.f,0.f}; acc[mi][ni]=zv; }
  #pragma unroll
  for (int k0=0; k0<DIN; k0+=32){
    bf16x8 aj[4], wh[4];
    #pragma unroll
    for (int mi=0;mi<4;mi++)
      aj[mi] = *(const bf16x8*)&lds[(wm+mi*16+rl)*DIN + ((k0+ksb*8) ^ xr)];
    #pragma unroll
    for (int ni=0;ni<4;ni++)
      wh[ni] = *(const bf16x8*)&lds[JW1 + (wn+ni*16+rl)*DIN + ((k0+ksb*8) ^ xr)];
    #pragma unroll
    for (int ni=0;ni<4;ni++)
      #pragma unroll
      for (int mi=0;mi<4;mi++)
        acc[mi][ni] = __builtin_amdgcn_mfma_f32_16x16x32_bf16(aj[mi], wh[ni], acc[mi][ni], 0,0,0);
  }
  __syncthreads();                              // lJ/lW1 reads done everywhere

  float bh[4];
  #pragma unroll
  for (int ni=0;ni<4;ni++) bh[ni] = b1g[k*128 + wn + ni*16 + rl];
  #pragma unroll
  for (int ni=0;ni<4;ni++){
    const int h = wn + ni*16 + rl;
    #pragma unroll
    for (int mi=0;mi<4;mi++){
      #pragma unroll
      for (int r=0;r<4;r++){
        const int j = wm + mi*16 + ksb*4 + r;
        const float v = fmaxf(acc[mi][ni][r] + bh[ni], 0.f);
        lds[j*128 + (h ^ ((j&7)<<3))] = f2bf(v);   // lM1 @0
      }
    }
  }
  __syncthreads();                              // M1 visible; lW2 landed

  // stage 2: C2[o][j] = sum_h W2T[o][h]*M1[j][h]
  f32x4 acc2[4][4];
  #pragma unroll
  for (int mi=0;mi<4;mi++)
    #pragma unroll
    for (int ni=0;ni<4;ni++){ f32x4 zv={0.f,0.f,0.f,0.f}; acc2[mi][ni]=zv; }
  #pragma unroll
  for (int k0=0; k0<128; k0+=32){
    bf16x8 ao[4], mj[4];
    #pragma unroll
    for (int mi=0;mi<4;mi++)
      ao[mi] = *(const bf16x8*)&lds[2*JW1 + (wm+mi*16+rl)*128 + ((k0+ksb*8) ^ xr)];
    #pragma unroll
    for (int ni=0;ni<4;ni++)
      mj[ni] = *(const bf16x8*)&lds[(wn+ni*16+rl)*128 + ((k0+ksb*8) ^ xr)];
    #pragma unroll
    for (int ni=0;ni<4;ni++)
      #pragma unroll
      for (int mi=0;mi<4;mi++)
        acc2[mi][ni] = __builtin_amdgcn_mfma_f32_16x16x32_bf16(ao[mi], mj[ni], acc2[mi][ni], 0,0,0);
  }

  const float ws = wsl[k];
  #pragma unroll
  for (int mi=0;mi<4;mi++){
    #pragma unroll
    for (int r=0;r<4;r++){
      const int o = wm + mi*16 + ksb*4 + r;
      const float bo = b2g[k*128 + o];
      #pragma unroll
      for (int ni=0;ni<4;ni++){
        const int j = wn + ni*16 + rl;
        const float v = (acc2[mi][ni][r] + bo) * ws;
        M2T[(size_t)(b*128 + o)*3072 + k*1024 + jt*128 + j] = f2bf(v);
      }
    }
  }
}

// ---------------- pooling + head ----------------
__global__ void pool_kernel(const u16* __restrict__ H, float* __restrict__ pooled){
  const int row = blockIdx.x, t = threadIdx.x;
  u16x4 v = *(const u16x4*)(H + (size_t)row*1024 + t*4);
  float s = bf2f(v.x)+bf2f(v.y)+bf2f(v.z)+bf2f(v.w);
  for (int o2=32;o2>0;o2>>=1) s += __shfl_down(s,o2);
  __shared__ float red[4];
  if ((t&63)==0) red[t>>6]=s;
  __syncthreads();
  if (t==0) pooled[row] = (red[0]+red[1]+red[2]+red[3])*(1.f/1024.f);
}

__global__ void head_kernel(const float* __restrict__ pooled, const float* __restrict__ Wc1,
                            const float* __restrict__ bc1, const float* __restrict__ alpha,
                            const float* __restrict__ Wc2, const float* __restrict__ bc2,
                            float* __restrict__ out){
  const int b = blockIdx.x, h = threadIdx.x;
  __shared__ float p[128], zz[128];
  p[h] = pooled[b*128+h];
  __syncthreads();
  float acc = bc1[h];
  for (int d=0; d<128; d++) acc = fmaf(p[d], Wc1[d*128+h], acc);
  zz[h] = acc>0.f ? acc : alpha[h]*acc;    // PReLU
  __syncthreads();
  if (h<4){
    float a = bc2[h];
    for (int q=0;q<128;q++) a = fmaf(zz[q], Wc2[q*4+h], a);
    out[b*4+h]=a;
  }
}

// ---------------- launcher ----------------
extern "C" void kernel_launch(void* const* d_in, const int* in_sizes, int n_in,
                              void* d_out, int out_size, void* d_ws, size_t ws_size,
                              hipStream_t stream)
{
  const float* x     = (const float*)d_in[0];
  const float* U     = (const float*)d_in[1];
  const float* w1_0  = (const float*)d_in[2];
  const float* b1_0  = (const float*)d_in[3];
  const float* w2_0  = (const float*)d_in[4];
  const float* b2_0  = (const float*)d_in[5];
  const float* w1_r  = (const float*)d_in[6];
  const float* b1_r  = (const float*)d_in[7];
  const float* w2_r  = (const float*)d_in[8];
  const float* b2_r  = (const float*)d_in[9];
  const float* bw    = (const float*)d_in[10];
  const float* Wc1   = (const float*)d_in[11];
  const float* bc1   = (const float*)d_in[12];
  const float* alpha = (const float*)d_in[13];
  const float* Wc2   = (const float*)d_in[14];
  const float* bc2   = (const float*)d_in[15];
  float* out = (float*)d_out;

  char* wsp = (char*)d_ws;
  size_t off = 0;
  auto alloc = [&](size_t bytes) -> void* {
    void* p = wsp + off;
    off = (off + bytes + 255) & ~(size_t)255;
    return p;
  };
  u16* UTcat = (u16*)alloc(6291456);     // [3][1024][1024]
  u16* Ucat  = (u16*)alloc(6291456);     // [1024][3072]
  u16* W1T0  = (u16*)alloc(49152);
  u16* W2T0  = (u16*)alloc(98304);
  u16* W1Tr  = (u16*)alloc(196608);
  u16* W2Tr  = (u16*)alloc(196608);
  float* wsb = (float*)alloc(256);
  u16* HT    = (u16*)alloc(16777216);    // [8192][1024]
  u16* AGG   = (u16*)alloc(50331648);    // AGG2 [(k,b,j)][Din]
  u16* M2T   = (u16*)alloc(50331648);    // [8192][3072]
  float* pooled = (float*)alloc(32768);
  if (off > ws_size) return;

  prep_weights<<<1056, 256, 0, stream>>>(w1_0,w2_0,w1_r,w2_r,bw,
      W1T0,W2T0,W1Tr,W2Tr,wsb);
  prep_U<<<dim3(32,32,3), dim3(32,8), 0, stream>>>(U, UTcat, Ucat);
  prep_x<<<dim3(2,32,64), dim3(32,8), 0, stream>>>(x, HT);

  for (int l=0; l<3; l++){
    const u16* w1t = l ? W1Tr + (size_t)(l-1)*3*16384 : W1T0;
    const u16* w2t = l ? W2Tr + (size_t)(l-1)*3*16384 : W2T0;
    const float* b1 = l ? b1_r + (l-1)*384 : b1_0;
    const float* b2 = l ? b2_r + (l-1)*384 : b2_0;

    // AGG2[((k*64+b)*1024+j)][d] = (U_k^T @ H) row-reordered
    if (l == 0)
      gemm_big<false,6><<<dim3(32, 4, 3), 512, 0, stream>>>(
          UTcat, HT, AGG, 4096, 1024, 1048576L, 0);
    else
      gemm_big<false,7><<<dim3(64, 4, 3), 512, 0, stream>>>(
          UTcat, HT, AGG, 8192, 1024, 1048576L, 0);
    // fused MLP: M2T[(b,o)][(k,j)] = ws_k*(relu(AGG2@W1+b1)@W2 + b2)
    if (l == 0)
      fused_mlp<64><<<dim3(8, 1, 192), 256, 0, stream>>>(
          AGG, w1t, w2t, b1, b2, wsb + l*3, M2T);
    else
      fused_mlp<128><<<dim3(8, 1, 192), 256, 0, stream>>>(
          AGG, w1t, w2t, b1, b2, wsb + l*3, M2T);
    // HT = relu(M2T @ Ucat) : one K=3072 GEMM sums all 3 branches
    gemm_big<true,0><<<dim3(8, 32, 1), 512, 0, stream>>>(
        M2T, Ucat, HT, 1024, 3072, 0L, 0);
  }
  pool_kernel<<<8192, 256, 0, stream>>>(HT, pooled);
  head_kernel<<<64, 128, 0, stream>>>(pooled, Wc1, bc1, alpha, Wc2, bc2, out);
}

// Round 10
// 412.980 us; speedup vs baseline: 2.6300x; 2.6300x over previous
//
#include <hip/hip_runtime.h>

// Graph_CNN_ortega — pure-bf16 MFMA. r6 structure (256x128, BK=32, ring-3,
// counted vmcnt(3), chunk swizzle) restored everywhere. NEW: for l>=1 the
// entire MLP (M1=relu(AGG@W1+b1); M2T=(W2@M1^T+b2)*ws) runs in the AGG
// kernel's epilogue (AGG tile = one b's full Din=128), eliminating the
// 100MB/layer AGG round-trip and 2 dispatches. l0 + OUT byte-identical r6.

typedef unsigned short u16;
typedef short bf16x8 __attribute__((ext_vector_type(8)));
typedef float f32x4 __attribute__((ext_vector_type(4)));
typedef u16 u16x4 __attribute__((ext_vector_type(4)));

__device__ __forceinline__ u16 f2bf(float x){
  unsigned u = __builtin_bit_cast(unsigned, x);
  u += 0x7fffu + ((u >> 16) & 1u);          // RNE
  return (u16)(u >> 16);
}
__device__ __forceinline__ float bf2f(u16 h){
  return __builtin_bit_cast(float, ((unsigned)h) << 16);
}
__device__ __forceinline__ void gload16(const u16* g, u16* l){
  __builtin_amdgcn_global_load_lds(
      (const __attribute__((address_space(1))) unsigned int*)(g),
      (__attribute__((address_space(3))) unsigned int*)(l), 16, 0, 0);
}

// ---------------- preprocessing ----------------

__global__ void prep_weights(const float* __restrict__ w1_0, const float* __restrict__ w2_0,
                             const float* __restrict__ w1_r, const float* __restrict__ w2_r,
                             const float* __restrict__ bw,
                             u16* __restrict__ W1T0, u16* __restrict__ W2T0,
                             u16* __restrict__ W1Tr, u16* __restrict__ W2Tr,
                             float* __restrict__ wsb){
  int id = blockIdx.x*256 + threadIdx.x;
  if (id < 3){
    float a0=bw[id*3+0], a1=bw[id*3+1], a2=bw[id*3+2];
    float m = fmaxf(a0,fmaxf(a1,a2));
    float e0=expf(a0-m), e1=expf(a1-m), e2=expf(a2-m);
    float s = e0+e1+e2;
    wsb[id*3+0]=e0/s; wsb[id*3+1]=e1/s; wsb[id*3+2]=e2/s;
  }
  if (id < 24576){                       // W1T0[k][h][d]=w1_0[k][d][h], d<64
    int k=id/8192, rem=id%8192, h=rem/64, d=rem%64;
    W1T0[id] = f2bf(w1_0[(k*64+d)*128 + h]);
  } else if (id < 73728){                // W2T0[k][o][h]=w2_0[k][h][o]
    int t=id-24576, k=t/16384, rem=t%16384, o=rem/128, h=rem%128;
    W2T0[t] = f2bf(w2_0[(k*128+h)*128 + o]);
  } else if (id < 172032){               // W1Tr[lk][h][d]=w1_r[lk][d][h]
    int t=id-73728, lk=t/16384, rem=t%16384, h=rem/128, d=rem%128;
    W1Tr[t] = f2bf(w1_r[lk*16384 + d*128 + h]);
  } else if (id < 270336){               // W2Tr[lk][o][h]=w2_r[lk][h][o]
    int t=id-172032, lk=t/16384, rem=t%16384, o=rem/128, h=rem%128;
    W2Tr[t] = f2bf(w2_r[lk*16384 + h*128 + o]);
  }
}

// U[3][1024][1024] f32 -> UTcat[k][i][j]=U[k][j][i] and Ucat[i][k*1024+j]
__global__ void prep_U(const float* __restrict__ U, u16* __restrict__ UTcat,
                       u16* __restrict__ Ucat){
  __shared__ float t[32][33];
  int k = blockIdx.z, i0 = blockIdx.x*32, j0 = blockIdx.y*32;
  size_t kb = (size_t)k << 20;
  #pragma unroll
  for (int rr=0; rr<4; rr++){
    int r = threadIdx.y*4+rr, c = threadIdx.x;
    float v = U[kb + (size_t)(j0+r)*1024 + i0+c];
    t[r][c] = v;
    Ucat[(size_t)(j0+r)*3072 + k*1024 + i0+c] = f2bf(v);
  }
  __syncthreads();
  #pragma unroll
  for (int rr=0; rr<4; rr++){
    int r = threadIdx.y*4+rr, c = threadIdx.x;
    UTcat[kb + (size_t)(i0+r)*1024 + j0+c] = f2bf(t[c][r]);
  }
}

// x[b][j][d] -> HT0[(b*64+d)][j] bf16
__global__ void prep_x(const float* __restrict__ x, u16* __restrict__ H){
  __shared__ float t[32][33];
  int b = blockIdx.z, d0 = blockIdx.x*32, j0 = blockIdx.y*32;
  #pragma unroll
  for (int rr=0;rr<4;rr++){
    int r=threadIdx.y*4+rr, c=threadIdx.x;
    t[r][c] = x[((size_t)b*1024 + j0+r)*64 + d0+c];
  }
  __syncthreads();
  #pragma unroll
  for (int rr=0;rr<4;rr++){
    int r=threadIdx.y*4+rr, c=threadIdx.x;
    H[(size_t)(b*64 + d0+r)*1024 + j0+c] = f2bf(t[c][r]);
  }
}

// ---------------- big NT GEMM (r6): 256x128, BK=32, ring-3, vmcnt(3) -------
template<bool RELU, int REORD>
__global__ __launch_bounds__(512, 4)
void gemm_big(const u16* __restrict__ A, const u16* __restrict__ B,
              u16* __restrict__ C, int Nc, int K, long aZ, int cRowZ)
{
  __shared__ __align__(16) u16 ldsA[3*8192];   // 3 x [256][32]  (48 KB)
  __shared__ __align__(16) u16 ldsB[3*4096];   // 3 x [128][32]  (24 KB)
  const int tid = threadIdx.x;
  const int z = blockIdx.z;
  const u16* Ab = A + (size_t)z*aZ;
  const int gx = gridDim.x;
  const int nwg = gx*gridDim.y;
  int flat = blockIdx.y*gx + blockIdx.x;
  if ((nwg & 7) == 0) flat = (flat & 7)*(nwg >> 3) + (flat >> 3);  // T1 XCD swizzle
  const int bm = (flat/gx)*256, bn = (flat%gx)*128;
  const int wave = tid>>6, lane = tid&63;
  const int wm = (wave&3)*64, wn = (wave>>2)*64;
  const int rl = lane&15, ksb = lane>>4;
  const int srow = tid>>2;
  const int scol = ((tid&3)*8) ^ (((tid>>3)&3)<<3);
  const int NT = K>>5;

  f32x4 acc[4][4];
  #pragma unroll
  for (int mi=0;mi<4;mi++)
    #pragma unroll
    for (int ni=0;ni<4;ni++){ f32x4 zv={0.f,0.f,0.f,0.f}; acc[mi][ni]=zv; }

  auto stage = [&](int t){
    const int sa = (t%3)*8192, sb = (t%3)*4096;
    const int k0 = t<<5;
    #pragma unroll
    for (int c=0;c<2;c++)
      gload16(Ab + (size_t)(bm + c*128 + srow)*K + k0 + scol,
              &ldsA[sa + c*4096 + tid*8]);
    gload16(B + (size_t)(bn + srow)*K + k0 + scol, &ldsB[sb + tid*8]);
  };

  stage(0); stage(1);
  asm volatile("s_waitcnt vmcnt(3)" ::: "memory");
  __builtin_amdgcn_s_barrier();
  __builtin_amdgcn_sched_barrier(0);

  for (int t=0; t<NT; t++){
    const int sa = (t%3)*8192, sb = (t%3)*4096;
    bf16x8 af[4], bfr[4];
    #pragma unroll
    for (int mi=0;mi<4;mi++){
      const int row = wm + mi*16 + rl;
      af[mi] = *(const bf16x8*)&ldsA[sa + row*32 + ((ksb*8) ^ (((row>>1)&3)<<3))];
    }
    #pragma unroll
    for (int ni=0;ni<4;ni++){
      const int row = wn + ni*16 + rl;
      bfr[ni] = *(const bf16x8*)&ldsB[sb + row*32 + ((ksb*8) ^ (((row>>1)&3)<<3))];
    }
    if (t+2 < NT) stage(t+2);
    __builtin_amdgcn_s_setprio(1);
    #pragma unroll
    for (int ni=0;ni<4;ni++)
      #pragma unroll
      for (int mi=0;mi<4;mi++)
        acc[mi][ni] = __builtin_amdgcn_mfma_f32_16x16x32_bf16(af[mi], bfr[ni], acc[mi][ni], 0,0,0);
    __builtin_amdgcn_s_setprio(0);
    if (t+2 < NT)      asm volatile("s_waitcnt vmcnt(3)" ::: "memory");
    else if (t+1 < NT) asm volatile("s_waitcnt vmcnt(0)" ::: "memory");
    __builtin_amdgcn_s_barrier();
    __builtin_amdgcn_sched_barrier(0);
  }

  #pragma unroll
  for (int ni=0;ni<4;ni++){
    const int col = bn + wn + ni*16 + rl;
    #pragma unroll
    for (int mi=0;mi<4;mi++){
      const int row0 = bm + wm + mi*16 + ksb*4;          // m89 C layout
      #pragma unroll
      for (int r=0;r<4;r++){
        float v = acc[mi][ni][r];
        if (RELU) v = fmaxf(v, 0.f);
        if constexpr (REORD){
          const int Din = 1 << REORD;
          const int bb = col >> REORD, d = col & (Din-1);
          C[((size_t)((z<<6) + bb)*1024 + row0 + r)*Din + d] = f2bf(v);
        } else {
          C[(size_t)(z*cRowZ + row0 + r)*Nc + col] = f2bf(v);
        }
      }
    }
  }
}

// ---------------- fused AGG+MLP (l>=1, Din=128) ----------------
// K-loop identical to gemm_big. Block covers 256 j x one b's full d=0..127.
// Epilogue: acc -> LDS (bf16, XOR swz) -> M1=relu(@W1+b1) -> LDS -> M2T =
// (W2@M1^T + b2)*ws written directly. W1T/W2T staged to LDS[36864+] at kernel
// start (prologue vmcnt(3) provably drains them; in-loop counts unaffected).
__global__ __launch_bounds__(512, 2)
void gemm_agg_mlp(const u16* __restrict__ A, const u16* __restrict__ B,
                  const u16* __restrict__ W1T, const u16* __restrict__ W2T,
                  const float* __restrict__ b1g, const float* __restrict__ b2g,
                  const float* __restrict__ wsl, u16* __restrict__ M2T)
{
  // [0,24576) ringA | [24576,36864) ringB | [36864,53248) W1T | [53248,69632) W2T
  // exchange lM[256][128] = [0,32768) (reused after K-loop)
  __shared__ __align__(16) u16 lds[69632];     // 136 KB
  const int tid = threadIdx.x;
  const int z = blockIdx.z;                     // branch k
  const int K = 1024, NT = 32;
  const u16* Ab = A + (size_t)z*1048576;
  const u16* W1k = W1T + z*16384;
  const u16* W2k = W2T + z*16384;
  const int gx = gridDim.x;                     // 64
  const int nwg = gx*gridDim.y;                 // 256
  int flat = blockIdx.y*gx + blockIdx.x;
  if ((nwg & 7) == 0) flat = (flat & 7)*(nwg >> 3) + (flat >> 3);
  const int bm = (flat/gx)*256, bn = (flat%gx)*128;   // j-base, (b*128)
  const int b = bn >> 7;
  const int wave = tid>>6, lane = tid&63;
  const int wm = (wave&3)*64, wn = (wave>>2)*64;
  const int rl = lane&15, ksb = lane>>4;
  const int xr = (rl&7)<<3;
  const int srow = tid>>2;
  const int scol = ((tid&3)*8) ^ (((tid>>3)&3)<<3);

  f32x4 acc[4][4];
  #pragma unroll
  for (int mi=0;mi<4;mi++)
    #pragma unroll
    for (int ni=0;ni<4;ni++){ f32x4 zv={0.f,0.f,0.f,0.f}; acc[mi][ni]=zv; }

  // stage weights first (8 gloads) — drained by the prologue vmcnt(3)
  #pragma unroll
  for (int c=0;c<4;c++){
    const int e = c*4096 + tid*8, row = e>>7, col = e&127;
    gload16(W1k + row*128 + (col ^ ((row&7)<<3)), &lds[36864 + e]);
  }
  #pragma unroll
  for (int c=0;c<4;c++){
    const int e = c*4096 + tid*8, row = e>>7, col = e&127;
    gload16(W2k + row*128 + (col ^ ((row&7)<<3)), &lds[53248 + e]);
  }

  auto stage = [&](int t){
    const int sa = (t%3)*8192, sb = 24576 + (t%3)*4096;
    const int k0 = t<<5;
    #pragma unroll
    for (int c=0;c<2;c++)
      gload16(Ab + (size_t)(bm + c*128 + srow)*K + k0 + scol,
              &lds[sa + c*4096 + tid*8]);
    gload16(B + (size_t)(bn + srow)*K + k0 + scol, &lds[sb + tid*8]);
  };

  stage(0); stage(1);
  asm volatile("s_waitcnt vmcnt(3)" ::: "memory");   // weights + tile0 landed
  __builtin_amdgcn_s_barrier();
  __builtin_amdgcn_sched_barrier(0);

  for (int t=0; t<NT; t++){
    const int sa = (t%3)*8192, sb = 24576 + (t%3)*4096;
    bf16x8 af[4], bfr[4];
    #pragma unroll
    for (int mi=0;mi<4;mi++){
      const int row = wm + mi*16 + rl;
      af[mi] = *(const bf16x8*)&lds[sa + row*32 + ((ksb*8) ^ (((row>>1)&3)<<3))];
    }
    #pragma unroll
    for (int ni=0;ni<4;ni++){
      const int row = wn + ni*16 + rl;
      bfr[ni] = *(const bf16x8*)&lds[sb + row*32 + ((ksb*8) ^ (((row>>1)&3)<<3))];
    }
    if (t+2 < NT) stage(t+2);
    __builtin_amdgcn_s_setprio(1);
    #pragma unroll
    for (int ni=0;ni<4;ni++)
      #pragma unroll
      for (int mi=0;mi<4;mi++)
        acc[mi][ni] = __builtin_amdgcn_mfma_f32_16x16x32_bf16(af[mi], bfr[ni], acc[mi][ni], 0,0,0);
    __builtin_amdgcn_s_setprio(0);
    if (t+2 < NT)      asm volatile("s_waitcnt vmcnt(3)" ::: "memory");
    else if (t+1 < NT) asm volatile("s_waitcnt vmcnt(0)" ::: "memory");
    __builtin_amdgcn_s_barrier();
    __builtin_amdgcn_sched_barrier(0);
  }

  // ---- step A: acc -> lM[j][d] bf16 (XOR swz keyed j&7) ----
  __syncthreads();                               // all K-loop LDS reads done
  #pragma unroll
  for (int ni=0;ni<4;ni++){
    const int d = wn + ni*16 + rl;
    #pragma unroll
    for (int mi=0;mi<4;mi++){
      #pragma unroll
      for (int r=0;r<4;r++){
        const int j = wm + mi*16 + ksb*4 + r;
        lds[j*128 + (d ^ ((j&7)<<3))] = f2bf(acc[mi][ni][r]);
      }
    }
  }
  __syncthreads();

  // ---- step 2: M1[j][h] = relu(sum_d AGG2[j][d]*W1T[h][d] + b1) ----
  const int jg = (wave&3)*64, hg = (wave>>2)*64;
  f32x4 acc1[4][4];
  #pragma unroll
  for (int mi=0;mi<4;mi++)
    #pragma unroll
    for (int ni=0;ni<4;ni++){ f32x4 zv={0.f,0.f,0.f,0.f}; acc1[mi][ni]=zv; }
  #pragma unroll
  for (int kk=0;kk<4;kk++){
    const int k0 = kk*32;
    bf16x8 aj[4], wh[4];
    #pragma unroll
    for (int mi=0;mi<4;mi++)
      aj[mi] = *(const bf16x8*)&lds[(jg+mi*16+rl)*128 + ((k0+ksb*8) ^ xr)];
    #pragma unroll
    for (int ni=0;ni<4;ni++)
      wh[ni] = *(const bf16x8*)&lds[36864 + (hg+ni*16+rl)*128 + ((k0+ksb*8) ^ xr)];
    #pragma unroll
    for (int ni=0;ni<4;ni++)
      #pragma unroll
      for (int mi=0;mi<4;mi++)
        acc1[mi][ni] = __builtin_amdgcn_mfma_f32_16x16x32_bf16(aj[mi], wh[ni], acc1[mi][ni], 0,0,0);
  }
  __syncthreads();                               // lM reads done before overwrite

  float bh[4];
  #pragma unroll
  for (int ni=0;ni<4;ni++) bh[ni] = b1g[z*128 + hg + ni*16 + rl];
  #pragma unroll
  for (int ni=0;ni<4;ni++){
    const int h = hg + ni*16 + rl;
    #pragma unroll
    for (int mi=0;mi<4;mi++){
      #pragma unroll
      for (int r=0;r<4;r++){
        const int j = jg + mi*16 + ksb*4 + r;
        lds[j*128 + (h ^ ((j&7)<<3))] = f2bf(fmaxf(acc1[mi][ni][r] + bh[ni], 0.f));
      }
    }
  }
  __syncthreads();

  // ---- step 3: M2T[o][j] = (sum_h W2T[o][h]*M1[j][h] + b2)*ws ----
  const int og = (wave>>2)*64, jg2 = (wave&3)*64;
  f32x4 acc2[4][4];
  #pragma unroll
  for (int mi=0;mi<4;mi++)
    #pragma unroll
    for (int ni=0;ni<4;ni++){ f32x4 zv={0.f,0.f,0.f,0.f}; acc2[mi][ni]=zv; }
  #pragma unroll
  for (int kk=0;kk<4;kk++){
    const int k0 = kk*32;
    bf16x8 wo[4], mj[4];
    #pragma unroll
    for (int mi=0;mi<4;mi++)
      wo[mi] = *(const bf16x8*)&lds[53248 + (og+mi*16+rl)*128 + ((k0+ksb*8) ^ xr)];
    #pragma unroll
    for (int ni=0;ni<4;ni++)
      mj[ni] = *(const bf16x8*)&lds[(jg2+ni*16+rl)*128 + ((k0+ksb*8) ^ xr)];
    #pragma unroll
    for (int ni=0;ni<4;ni++)
      #pragma unroll
      for (int mi=0;mi<4;mi++)
        acc2[mi][ni] = __builtin_amdgcn_mfma_f32_16x16x32_bf16(wo[mi], mj[ni], acc2[mi][ni], 0,0,0);
  }

  const float ws = wsl[z];
  #pragma unroll
  for (int mi=0;mi<4;mi++){
    #pragma unroll
    for (int r=0;r<4;r++){
      const int o = og + mi*16 + ksb*4 + r;
      const float bo = b2g[z*128 + o];
      #pragma unroll
      for (int ni=0;ni<4;ni++){
        const int j = jg2 + ni*16 + rl;
        M2T[(size_t)(b*128 + o)*3072 + z*1024 + bm + j] = f2bf((acc2[mi][ni][r] + bo) * ws);
      }
    }
  }
}

// ---------------- fused MLP (l0 only, Din=64) ----------------
template<int DIN>
__global__ __launch_bounds__(256)
void fused_mlp(const u16* __restrict__ AGG, const u16* __restrict__ W1T,
               const u16* __restrict__ W2T, const float* __restrict__ b1g,
               const float* __restrict__ b2g, const float* __restrict__ wsl,
               u16* __restrict__ M2T)
{
  constexpr int JW1 = 128*DIN;
  __shared__ __align__(16) u16 lds[2*JW1 + 16384];
  const int tid = threadIdx.x;
  const int jt = blockIdx.x, z = blockIdx.z, k = z>>6, b = z&63;
  const u16* Ag  = AGG + ((size_t)z*1024 + jt*128)*DIN;
  const u16* W1k = W1T + k*JW1;
  const u16* W2k = W2T + k*16384;
  const int wave = tid>>6, lane = tid&63;
  const int wm = (wave>>1)*64, wn = (wave&1)*64;
  const int rl = lane&15, ksb = lane>>4;
  const int xr = (rl&7)<<3;

  constexpr int CJ = JW1/2048;
  #pragma unroll
  for (int c=0;c<CJ;c++){
    const int e = c*2048 + tid*8, row = e/DIN, col = e%DIN;
    gload16(Ag + (size_t)row*DIN + (col ^ ((row&7)<<3)), &lds[e]);
  }
  #pragma unroll
  for (int c=0;c<CJ;c++){
    const int e = c*2048 + tid*8, row = e/DIN, col = e%DIN;
    gload16(W1k + (size_t)row*DIN + (col ^ ((row&7)<<3)), &lds[JW1 + e]);
  }
  #pragma unroll
  for (int c=0;c<8;c++){
    const int e = c*2048 + tid*8, row = e>>7, col = e&127;
    gload16(W2k + (size_t)row*128 + (col ^ ((row&7)<<3)), &lds[2*JW1 + e]);
  }
  asm volatile("s_waitcnt vmcnt(8)" ::: "memory");
  __builtin_amdgcn_s_barrier();
  __builtin_amdgcn_sched_barrier(0);

  f32x4 acc[4][4];
  #pragma unroll
  for (int mi=0;mi<4;mi++)
    #pragma unroll
    for (int ni=0;ni<4;ni++){ f32x4 zv={0.f,0.f,0.f,0.f}; acc[mi][ni]=zv; }
  #pragma unroll
  for (int k0=0; k0<DIN; k0+=32){
    bf16x8 aj[4], wh[4];
    #pragma unroll
    for (int mi=0;mi<4;mi++)
      aj[mi] = *(const bf16x8*)&lds[(wm+mi*16+rl)*DIN + ((k0+ksb*8) ^ xr)];
    #pragma unroll
    for (int ni=0;ni<4;ni++)
      wh[ni] = *(const bf16x8*)&lds[JW1 + (wn+ni*16+rl)*DIN + ((k0+ksb*8) ^ xr)];
    #pragma unroll
    for (int ni=0;ni<4;ni++)
      #pragma unroll
      for (int mi=0;mi<4;mi++)
        acc[mi][ni] = __builtin_amdgcn_mfma_f32_16x16x32_bf16(aj[mi], wh[ni], acc[mi][ni], 0,0,0);
  }
  __syncthreads();

  float bh[4];
  #pragma unroll
  for (int ni=0;ni<4;ni++) bh[ni] = b1g[k*128 + wn + ni*16 + rl];
  #pragma unroll
  for (int ni=0;ni<4;ni++){
    const int h = wn + ni*16 + rl;
    #pragma unroll
    for (int mi=0;mi<4;mi++){
      #pragma unroll
      for (int r=0;r<4;r++){
        const int j = wm + mi*16 + ksb*4 + r;
        lds[j*128 + (h ^ ((j&7)<<3))] = f2bf(fmaxf(acc[mi][ni][r] + bh[ni], 0.f));
      }
    }
  }
  __syncthreads();

  f32x4 acc2[4][4];
  #pragma unroll
  for (int mi=0;mi<4;mi++)
    #pragma unroll
    for (int ni=0;ni<4;ni++){ f32x4 zv={0.f,0.f,0.f,0.f}; acc2[mi][ni]=zv; }
  #pragma unroll
  for (int k0=0; k0<128; k0+=32){
    bf16x8 ao[4], mj[4];
    #pragma unroll
    for (int mi=0;mi<4;mi++)
      ao[mi] = *(const bf16x8*)&lds[2*JW1 + (wm+mi*16+rl)*128 + ((k0+ksb*8) ^ xr)];
    #pragma unroll
    for (int ni=0;ni<4;ni++)
      mj[ni] = *(const bf16x8*)&lds[(wn+ni*16+rl)*128 + ((k0+ksb*8) ^ xr)];
    #pragma unroll
    for (int ni=0;ni<4;ni++)
      #pragma unroll
      for (int mi=0;mi<4;mi++)
        acc2[mi][ni] = __builtin_amdgcn_mfma_f32_16x16x32_bf16(ao[mi], mj[ni], acc2[mi][ni], 0,0,0);
  }

  const float ws = wsl[k];
  #pragma unroll
  for (int mi=0;mi<4;mi++){
    #pragma unroll
    for (int r=0;r<4;r++){
      const int o = wm + mi*16 + ksb*4 + r;
      const float bo = b2g[k*128 + o];
      #pragma unroll
      for (int ni=0;ni<4;ni++){
        const int j = wn + ni*16 + rl;
        M2T[(size_t)(b*128 + o)*3072 + k*1024 + jt*128 + j] = f2bf((acc2[mi][ni][r] + bo) * ws);
      }
    }
  }
}

// ---------------- pooling + head ----------------
__global__ void pool_kernel(const u16* __restrict__ H, float* __restrict__ pooled){
  const int row = blockIdx.x, t = threadIdx.x;
  u16x4 v = *(const u16x4*)(H + (size_t)row*1024 + t*4);
  float s = bf2f(v.x)+bf2f(v.y)+bf2f(v.z)+bf2f(v.w);
  for (int o2=32;o2>0;o2>>=1) s += __shfl_down(s,o2);
  __shared__ float red[4];
  if ((t&63)==0) red[t>>6]=s;
  __syncthreads();
  if (t==0) pooled[row] = (red[0]+red[1]+red[2]+red[3])*(1.f/1024.f);
}

__global__ void head_kernel(const float* __restrict__ pooled, const float* __restrict__ Wc1,
                            const float* __restrict__ bc1, const float* __restrict__ alpha,
                            const float* __restrict__ Wc2, const float* __restrict__ bc2,
                            float* __restrict__ out){
  const int b = blockIdx.x, h = threadIdx.x;
  __shared__ float p[128], zz[128];
  p[h] = pooled[b*128+h];
  __syncthreads();
  float acc = bc1[h];
  for (int d=0; d<128; d++) acc = fmaf(p[d], Wc1[d*128+h], acc);
  zz[h] = acc>0.f ? acc : alpha[h]*acc;    // PReLU
  __syncthreads();
  if (h<4){
    float a = bc2[h];
    for (int q=0;q<128;q++) a = fmaf(zz[q], Wc2[q*4+h], a);
    out[b*4+h]=a;
  }
}

// ---------------- launcher ----------------
extern "C" void kernel_launch(void* const* d_in, const int* in_sizes, int n_in,
                              void* d_out, int out_size, void* d_ws, size_t ws_size,
                              hipStream_t stream)
{
  const float* x     = (const float*)d_in[0];
  const float* U     = (const float*)d_in[1];
  const float* w1_0  = (const float*)d_in[2];
  const float* b1_0  = (const float*)d_in[3];
  const float* w2_0  = (const float*)d_in[4];
  const float* b2_0  = (const float*)d_in[5];
  const float* w1_r  = (const float*)d_in[6];
  const float* b1_r  = (const float*)d_in[7];
  const float* w2_r  = (const float*)d_in[8];
  const float* b2_r  = (const float*)d_in[9];
  const float* bw    = (const float*)d_in[10];
  const float* Wc1   = (const float*)d_in[11];
  const float* bc1   = (const float*)d_in[12];
  const float* alpha = (const float*)d_in[13];
  const float* Wc2   = (const float*)d_in[14];
  const float* bc2   = (const float*)d_in[15];
  float* out = (float*)d_out;

  char* wsp = (char*)d_ws;
  size_t off = 0;
  auto alloc = [&](size_t bytes) -> void* {
    void* p = wsp + off;
    off = (off + bytes + 255) & ~(size_t)255;
    return p;
  };
  u16* UTcat = (u16*)alloc(6291456);     // [3][1024][1024]
  u16* Ucat  = (u16*)alloc(6291456);     // [1024][3072]
  u16* W1T0  = (u16*)alloc(49152);
  u16* W2T0  = (u16*)alloc(98304);
  u16* W1Tr  = (u16*)alloc(196608);
  u16* W2Tr  = (u16*)alloc(196608);
  float* wsb = (float*)alloc(256);
  u16* HT    = (u16*)alloc(16777216);    // [8192][1024]
  u16* AGG   = (u16*)alloc(50331648);    // AGG2 (l0 only)
  u16* M2T   = (u16*)alloc(50331648);    // [8192][3072]
  float* pooled = (float*)alloc(32768);
  if (off > ws_size) return;

  prep_weights<<<1056, 256, 0, stream>>>(w1_0,w2_0,w1_r,w2_r,bw,
      W1T0,W2T0,W1Tr,W2Tr,wsb);
  prep_U<<<dim3(32,32,3), dim3(32,8), 0, stream>>>(U, UTcat, Ucat);
  prep_x<<<dim3(2,32,64), dim3(32,8), 0, stream>>>(x, HT);

  for (int l=0; l<3; l++){
    const float* b1 = l ? b1_r + (l-1)*384 : b1_0;
    const float* b2 = l ? b2_r + (l-1)*384 : b2_0;

    if (l == 0){
      // AGG2[((k*64+b)*1024+j)][d] then separate fused MLP (Din=64)
      gemm_big<false,6><<<dim3(32, 4, 3), 512, 0, stream>>>(
          UTcat, HT, AGG, 4096, 1024, 1048576L, 0);
      fused_mlp<64><<<dim3(8, 1, 192), 256, 0, stream>>>(
          AGG, W1T0, W2T0, b1, b2, wsb, M2T);
    } else {
      // AGG + full MLP fused: writes M2T directly (Din=128)
      gemm_agg_mlp<<<dim3(64, 4, 3), 512, 0, stream>>>(
          UTcat, HT,
          W1Tr + (size_t)(l-1)*3*16384, W2Tr + (size_t)(l-1)*3*16384,
          b1, b2, wsb + l*3, M2T);
    }
    // HT = relu(M2T @ Ucat) : one K=3072 GEMM sums all 3 branches
    gemm_big<true,0><<<dim3(8, 32, 1), 512, 0, stream>>>(
        M2T, Ucat, HT, 1024, 3072, 0L, 0);
  }
  pool_kernel<<<8192, 256, 0, stream>>>(HT, pooled);
  head_kernel<<<64, 128, 0, stream>>>(pooled, Wc1, bc1, alpha, Wc2, bc2, out);
}

// Round 11
// 408.797 us; speedup vs baseline: 2.6569x; 1.0102x over previous
//
#include <hip/hip_runtime.h>

// Graph_CNN_ortega — pure-bf16 MFMA. r10 structure, two fixes:
// (1) gemm_agg_mlp v2: 80KB LDS (2 blocks/CU) — weights as direct global
//     VGPR fragments, MLP epilogue in 4 j-quarter passes (lX 64KB + lM 16KB).
// (2) OUT l2 skips the HT write and pools in-register (shfl partials) ->
//     pool_kernel replaced by a tiny combine. B=64,N=1024,DIN=64,DH=128,L=3.

typedef unsigned short u16;
typedef short bf16x8 __attribute__((ext_vector_type(8)));
typedef float f32x4 __attribute__((ext_vector_type(4)));
typedef u16 u16x4 __attribute__((ext_vector_type(4)));

__device__ __forceinline__ u16 f2bf(float x){
  unsigned u = __builtin_bit_cast(unsigned, x);
  u += 0x7fffu + ((u >> 16) & 1u);          // RNE
  return (u16)(u >> 16);
}
__device__ __forceinline__ float bf2f(u16 h){
  return __builtin_bit_cast(float, ((unsigned)h) << 16);
}
__device__ __forceinline__ void gload16(const u16* g, u16* l){
  __builtin_amdgcn_global_load_lds(
      (const __attribute__((address_space(1))) unsigned int*)(g),
      (__attribute__((address_space(3))) unsigned int*)(l), 16, 0, 0);
}

// ---------------- preprocessing ----------------

__global__ void prep_weights(const float* __restrict__ w1_0, const float* __restrict__ w2_0,
                             const float* __restrict__ w1_r, const float* __restrict__ w2_r,
                             const float* __restrict__ bw,
                             u16* __restrict__ W1T0, u16* __restrict__ W2T0,
                             u16* __restrict__ W1Tr, u16* __restrict__ W2Tr,
                             float* __restrict__ wsb){
  int id = blockIdx.x*256 + threadIdx.x;
  if (id < 3){
    float a0=bw[id*3+0], a1=bw[id*3+1], a2=bw[id*3+2];
    float m = fmaxf(a0,fmaxf(a1,a2));
    float e0=expf(a0-m), e1=expf(a1-m), e2=expf(a2-m);
    float s = e0+e1+e2;
    wsb[id*3+0]=e0/s; wsb[id*3+1]=e1/s; wsb[id*3+2]=e2/s;
  }
  if (id < 24576){                       // W1T0[k][h][d]=w1_0[k][d][h], d<64
    int k=id/8192, rem=id%8192, h=rem/64, d=rem%64;
    W1T0[id] = f2bf(w1_0[(k*64+d)*128 + h]);
  } else if (id < 73728){                // W2T0[k][o][h]=w2_0[k][h][o]
    int t=id-24576, k=t/16384, rem=t%16384, o=rem/128, h=rem%128;
    W2T0[t] = f2bf(w2_0[(k*128+h)*128 + o]);
  } else if (id < 172032){               // W1Tr[lk][h][d]=w1_r[lk][d][h]
    int t=id-73728, lk=t/16384, rem=t%16384, h=rem/128, d=rem%128;
    W1Tr[t] = f2bf(w1_r[lk*16384 + d*128 + h]);
  } else if (id < 270336){               // W2Tr[lk][o][h]=w2_r[lk][h][o]
    int t=id-172032, lk=t/16384, rem=t%16384, o=rem/128, h=rem%128;
    W2Tr[t] = f2bf(w2_r[lk*16384 + h*128 + o]);
  }
}

// U[3][1024][1024] f32 -> UTcat[k][i][j]=U[k][j][i] and Ucat[i][k*1024+j]
__global__ void prep_U(const float* __restrict__ U, u16* __restrict__ UTcat,
                       u16* __restrict__ Ucat){
  __shared__ float t[32][33];
  int k = blockIdx.z, i0 = blockIdx.x*32, j0 = blockIdx.y*32;
  size_t kb = (size_t)k << 20;
  #pragma unroll
  for (int rr=0; rr<4; rr++){
    int r = threadIdx.y*4+rr, c = threadIdx.x;
    float v = U[kb + (size_t)(j0+r)*1024 + i0+c];
    t[r][c] = v;
    Ucat[(size_t)(j0+r)*3072 + k*1024 + i0+c] = f2bf(v);
  }
  __syncthreads();
  #pragma unroll
  for (int rr=0; rr<4; rr++){
    int r = threadIdx.y*4+rr, c = threadIdx.x;
    UTcat[kb + (size_t)(i0+r)*1024 + j0+c] = f2bf(t[c][r]);
  }
}

// x[b][j][d] -> HT0[(b*64+d)][j] bf16
__global__ void prep_x(const float* __restrict__ x, u16* __restrict__ H){
  __shared__ float t[32][33];
  int b = blockIdx.z, d0 = blockIdx.x*32, j0 = blockIdx.y*32;
  #pragma unroll
  for (int rr=0;rr<4;rr++){
    int r=threadIdx.y*4+rr, c=threadIdx.x;
    t[r][c] = x[((size_t)b*1024 + j0+r)*64 + d0+c];
  }
  __syncthreads();
  #pragma unroll
  for (int rr=0;rr<4;rr++){
    int r=threadIdx.y*4+rr, c=threadIdx.x;
    H[(size_t)(b*64 + d0+r)*1024 + j0+c] = f2bf(t[c][r]);
  }
}

// ---------------- big NT GEMM (r6): 256x128, BK=32, ring-3, vmcnt(3) -------
// POOL=true (l2 OUT): skip HT write; per-row partial sums of relu(acc) via
// shfl reduce -> Pp[(bx*2+wnbit)][row] (deterministic, no atomics).
template<bool RELU, int REORD, bool POOL>
__global__ __launch_bounds__(512, 4)
void gemm_big(const u16* __restrict__ A, const u16* __restrict__ B,
              u16* __restrict__ C, float* __restrict__ Pp,
              int Nc, int K, long aZ, int cRowZ)
{
  __shared__ __align__(16) u16 ldsA[3*8192];   // 3 x [256][32]  (48 KB)
  __shared__ __align__(16) u16 ldsB[3*4096];   // 3 x [128][32]  (24 KB)
  const int tid = threadIdx.x;
  const int z = blockIdx.z;
  const u16* Ab = A + (size_t)z*aZ;
  const int gx = gridDim.x;
  const int nwg = gx*gridDim.y;
  int flat = blockIdx.y*gx + blockIdx.x;
  if ((nwg & 7) == 0) flat = (flat & 7)*(nwg >> 3) + (flat >> 3);  // T1 XCD swizzle
  const int bm = (flat/gx)*256, bn = (flat%gx)*128;
  const int wave = tid>>6, lane = tid&63;
  const int wm = (wave&3)*64, wn = (wave>>2)*64;
  const int rl = lane&15, ksb = lane>>4;
  const int srow = tid>>2;
  const int scol = ((tid&3)*8) ^ (((tid>>3)&3)<<3);
  const int NT = K>>5;

  f32x4 acc[4][4];
  #pragma unroll
  for (int mi=0;mi<4;mi++)
    #pragma unroll
    for (int ni=0;ni<4;ni++){ f32x4 zv={0.f,0.f,0.f,0.f}; acc[mi][ni]=zv; }

  auto stage = [&](int t){
    const int sa = (t%3)*8192, sb = (t%3)*4096;
    const int k0 = t<<5;
    #pragma unroll
    for (int c=0;c<2;c++)
      gload16(Ab + (size_t)(bm + c*128 + srow)*K + k0 + scol,
              &ldsA[sa + c*4096 + tid*8]);
    gload16(B + (size_t)(bn + srow)*K + k0 + scol, &ldsB[sb + tid*8]);
  };

  stage(0); stage(1);
  asm volatile("s_waitcnt vmcnt(3)" ::: "memory");
  __builtin_amdgcn_s_barrier();
  __builtin_amdgcn_sched_barrier(0);

  for (int t=0; t<NT; t++){
    const int sa = (t%3)*8192, sb = (t%3)*4096;
    bf16x8 af[4], bfr[4];
    #pragma unroll
    for (int mi=0;mi<4;mi++){
      const int row = wm + mi*16 + rl;
      af[mi] = *(const bf16x8*)&ldsA[sa + row*32 + ((ksb*8) ^ (((row>>1)&3)<<3))];
    }
    #pragma unroll
    for (int ni=0;ni<4;ni++){
      const int row = wn + ni*16 + rl;
      bfr[ni] = *(const bf16x8*)&ldsB[sb + row*32 + ((ksb*8) ^ (((row>>1)&3)<<3))];
    }
    if (t+2 < NT) stage(t+2);
    __builtin_amdgcn_s_setprio(1);
    #pragma unroll
    for (int ni=0;ni<4;ni++)
      #pragma unroll
      for (int mi=0;mi<4;mi++)
        acc[mi][ni] = __builtin_amdgcn_mfma_f32_16x16x32_bf16(af[mi], bfr[ni], acc[mi][ni], 0,0,0);
    __builtin_amdgcn_s_setprio(0);
    if (t+2 < NT)      asm volatile("s_waitcnt vmcnt(3)" ::: "memory");
    else if (t+1 < NT) asm volatile("s_waitcnt vmcnt(0)" ::: "memory");
    __builtin_amdgcn_s_barrier();
    __builtin_amdgcn_sched_barrier(0);
  }

  if constexpr (POOL){
    const int bx = flat % gx;                  // 0..7 (OUT: gx=8)
    #pragma unroll
    for (int mi=0;mi<4;mi++){
      #pragma unroll
      for (int r=0;r<4;r++){
        float s = 0.f;
        #pragma unroll
        for (int ni=0;ni<4;ni++) s += fmaxf(acc[mi][ni][r], 0.f);
        s += __shfl_xor(s, 1); s += __shfl_xor(s, 2);
        s += __shfl_xor(s, 4); s += __shfl_xor(s, 8);
        if ((lane & 15) == 0){
          const int row = bm + wm + mi*16 + ksb*4 + r;
          Pp[(size_t)(bx*2 + (wn>>6))*8192 + row] = s;
        }
      }
    }
    return;
  }

  #pragma unroll
  for (int ni=0;ni<4;ni++){
    const int col = bn + wn + ni*16 + rl;
    #pragma unroll
    for (int mi=0;mi<4;mi++){
      const int row0 = bm + wm + mi*16 + ksb*4;          // m89 C layout
      #pragma unroll
      for (int r=0;r<4;r++){
        float v = acc[mi][ni][r];
        if (RELU) v = fmaxf(v, 0.f);
        if constexpr (REORD){
          const int Din = 1 << REORD;
          const int bb = col >> REORD, d = col & (Din-1);
          C[((size_t)((z<<6) + bb)*1024 + row0 + r)*Din + d] = f2bf(v);
        } else {
          C[(size_t)(z*cRowZ + row0 + r)*Nc + col] = f2bf(v);
        }
      }
    }
  }
}

// ---------------- fused AGG+MLP v2 (l>=1, Din=128), 80KB LDS = 2 blocks/CU --
// K-loop identical to gemm_big. Epilogue: acc -> lX[256][128] (ring reuse),
// then 4 j-quarter passes: MLP1 (W1 frags direct from global) -> lM[64][128]
// -> MLP2 (W2 frags direct from global) -> M2T. No weight LDS staging.
__global__ __launch_bounds__(512, 4)
void gemm_agg_mlp(const u16* __restrict__ A, const u16* __restrict__ B,
                  const u16* __restrict__ W1T, const u16* __restrict__ W2T,
                  const float* __restrict__ b1g, const float* __restrict__ b2g,
                  const float* __restrict__ wsl, u16* __restrict__ M2T)
{
  // u16 elems: ringA [0,24576) | ringB [24576,36864) | lM [32768,40960)
  // lX [0,32768) (ring reuse after K-loop). Total 40960 u16 = 80 KB.
  __shared__ __align__(16) u16 lds[40960];
  const int tid = threadIdx.x;
  const int z = blockIdx.z;                     // branch k
  const int K = 1024, NT = 32;
  const u16* Ab = A + (size_t)z*1048576;
  const u16* W1k = W1T + z*16384;               // [128 h][128 d]
  const u16* W2k = W2T + z*16384;               // [128 o][128 h]
  const int gx = gridDim.x;                     // 64
  const int nwg = gx*gridDim.y;                 // 256
  int flat = blockIdx.y*gx + blockIdx.x;
  if ((nwg & 7) == 0) flat = (flat & 7)*(nwg >> 3) + (flat >> 3);
  const int bm = (flat/gx)*256, bn = (flat%gx)*128;   // j-base, (b*128)
  const int b = bn >> 7;
  const int wave = tid>>6, lane = tid&63;
  const int wm = (wave&3)*64, wn = (wave>>2)*64;
  const int rl = lane&15, ksb = lane>>4;
  const int xr = (rl&7)<<3;
  const int srow = tid>>2;
  const int scol = ((tid&3)*8) ^ (((tid>>3)&3)<<3);

  f32x4 acc[4][4];
  #pragma unroll
  for (int mi=0;mi<4;mi++)
    #pragma unroll
    for (int ni=0;ni<4;ni++){ f32x4 zv={0.f,0.f,0.f,0.f}; acc[mi][ni]=zv; }

  auto stage = [&](int t){
    const int sa = (t%3)*8192, sb = 24576 + (t%3)*4096;
    const int k0 = t<<5;
    #pragma unroll
    for (int c=0;c<2;c++)
      gload16(Ab + (size_t)(bm + c*128 + srow)*K + k0 + scol,
              &lds[sa + c*4096 + tid*8]);
    gload16(B + (size_t)(bn + srow)*K + k0 + scol, &lds[sb + tid*8]);
  };

  stage(0); stage(1);
  asm volatile("s_waitcnt vmcnt(3)" ::: "memory");
  __builtin_amdgcn_s_barrier();
  __builtin_amdgcn_sched_barrier(0);

  for (int t=0; t<NT; t++){
    const int sa = (t%3)*8192, sb = 24576 + (t%3)*4096;
    bf16x8 af[4], bfr[4];
    #pragma unroll
    for (int mi=0;mi<4;mi++){
      const int row = wm + mi*16 + rl;
      af[mi] = *(const bf16x8*)&lds[sa + row*32 + ((ksb*8) ^ (((row>>1)&3)<<3))];
    }
    #pragma unroll
    for (int ni=0;ni<4;ni++){
      const int row = wn + ni*16 + rl;
      bfr[ni] = *(const bf16x8*)&lds[sb + row*32 + ((ksb*8) ^ (((row>>1)&3)<<3))];
    }
    if (t+2 < NT) stage(t+2);
    __builtin_amdgcn_s_setprio(1);
    #pragma unroll
    for (int ni=0;ni<4;ni++)
      #pragma unroll
      for (int mi=0;mi<4;mi++)
        acc[mi][ni] = __builtin_amdgcn_mfma_f32_16x16x32_bf16(af[mi], bfr[ni], acc[mi][ni], 0,0,0);
    __builtin_amdgcn_s_setprio(0);
    if (t+2 < NT)      asm volatile("s_waitcnt vmcnt(3)" ::: "memory");
    else if (t+1 < NT) asm volatile("s_waitcnt vmcnt(0)" ::: "memory");
    __builtin_amdgcn_s_barrier();
    __builtin_amdgcn_sched_barrier(0);
  }

  // ---- exchange: ALL acc -> lX[256 j][128 d] (swz by j&7); acc dies ----
  __syncthreads();
  #pragma unroll
  for (int ni=0;ni<4;ni++){
    const int d = wn + ni*16 + rl;
    #pragma unroll
    for (int mi=0;mi<4;mi++){
      #pragma unroll
      for (int r=0;r<4;r++){
        const int j = wm + mi*16 + ksb*4 + r;
        lds[j*128 + (d ^ ((j&7)<<3))] = f2bf(acc[mi][ni][r]);
      }
    }
  }
  __syncthreads();

  const float ws = wsl[z];
  for (int p=0; p<4; p++){                      // j-quarter = 64 rows
    // MLP1: [64 j][128 h], K=128. wave -> hg = wave*16 (1 ni), 4 mi.
    const int hg = wave*16;
    const int h  = hg + rl;
    const float bh = b1g[z*128 + h];
    f32x4 acc1[4];
    #pragma unroll
    for (int mi=0;mi<4;mi++){ f32x4 zv={0.f,0.f,0.f,0.f}; acc1[mi]=zv; }
    #pragma unroll
    for (int kk=0;kk<4;kk++){
      const int k0 = kk*32;
      const bf16x8 wh = *(const bf16x8*)(W1k + (size_t)h*128 + k0 + ksb*8);
      #pragma unroll
      for (int mi=0;mi<4;mi++){
        const bf16x8 aj = *(const bf16x8*)&lds[(p*64+mi*16+rl)*128 + ((k0+ksb*8) ^ xr)];
        acc1[mi] = __builtin_amdgcn_mfma_f32_16x16x32_bf16(aj, wh, acc1[mi], 0,0,0);
      }
    }
    // M1 -> lM[64 j][128 h] @ u16 32768
    #pragma unroll
    for (int mi=0;mi<4;mi++){
      #pragma unroll
      for (int r=0;r<4;r++){
        const int jl = mi*16 + ksb*4 + r;
        lds[32768 + jl*128 + (h ^ ((jl&7)<<3))] = f2bf(fmaxf(acc1[mi][r] + bh, 0.f));
      }
    }
    __syncthreads();
    // MLP2: [128 o][64 j], K=128. wave -> og=(w>>1)*32 (2 mi), jg2=(w&1)*32 (2 ni)
    const int og = (wave>>1)*32, jg2 = (wave&1)*32;
    f32x4 acc2[2][2];
    #pragma unroll
    for (int mi=0;mi<2;mi++)
      #pragma unroll
      for (int ni=0;ni<2;ni++){ f32x4 zv={0.f,0.f,0.f,0.f}; acc2[mi][ni]=zv; }
    #pragma unroll
    for (int kk=0;kk<4;kk++){
      const int k0 = kk*32;
      bf16x8 wo[2], mj[2];
      #pragma unroll
      for (int mi=0;mi<2;mi++)
        wo[mi] = *(const bf16x8*)(W2k + (size_t)(og+mi*16+rl)*128 + k0 + ksb*8);
      #pragma unroll
      for (int ni=0;ni<2;ni++)
        mj[ni] = *(const bf16x8*)&lds[32768 + (jg2+ni*16+rl)*128 + ((k0+ksb*8) ^ xr)];
      #pragma unroll
      for (int ni=0;ni<2;ni++)
        #pragma unroll
        for (int mi=0;mi<2;mi++)
          acc2[mi][ni] = __builtin_amdgcn_mfma_f32_16x16x32_bf16(wo[mi], mj[ni], acc2[mi][ni], 0,0,0);
    }
    #pragma unroll
    for (int mi=0;mi<2;mi++){
      #pragma unroll
      for (int r=0;r<4;r++){
        const int o = og + mi*16 + ksb*4 + r;
        const float bo = b2g[z*128 + o];
        #pragma unroll
        for (int ni=0;ni<2;ni++){
          const int jl = jg2 + ni*16 + rl;
          M2T[(size_t)(b*128 + o)*3072 + z*1024 + bm + p*64 + jl]
              = f2bf((acc2[mi][ni][r] + bo) * ws);
        }
      }
    }
    __syncthreads();                            // lM safe to overwrite next p
  }
}

// ---------------- fused MLP (l0 only, Din=64) ----------------
template<int DIN>
__global__ __launch_bounds__(256)
void fused_mlp(const u16* __restrict__ AGG, const u16* __restrict__ W1T,
               const u16* __restrict__ W2T, const float* __restrict__ b1g,
               const float* __restrict__ b2g, const float* __restrict__ wsl,
               u16* __restrict__ M2T)
{
  constexpr int JW1 = 128*DIN;
  __shared__ __align__(16) u16 lds[2*JW1 + 16384];
  const int tid = threadIdx.x;
  const int jt = blockIdx.x, z = blockIdx.z, k = z>>6, b = z&63;
  const u16* Ag  = AGG + ((size_t)z*1024 + jt*128)*DIN;
  const u16* W1k = W1T + k*JW1;
  const u16* W2k = W2T + k*16384;
  const int wave = tid>>6, lane = tid&63;
  const int wm = (wave>>1)*64, wn = (wave&1)*64;
  const int rl = lane&15, ksb = lane>>4;
  const int xr = (rl&7)<<3;

  constexpr int CJ = JW1/2048;
  #pragma unroll
  for (int c=0;c<CJ;c++){
    const int e = c*2048 + tid*8, row = e/DIN, col = e%DIN;
    gload16(Ag + (size_t)row*DIN + (col ^ ((row&7)<<3)), &lds[e]);
  }
  #pragma unroll
  for (int c=0;c<CJ;c++){
    const int e = c*2048 + tid*8, row = e/DIN, col = e%DIN;
    gload16(W1k + (size_t)row*DIN + (col ^ ((row&7)<<3)), &lds[JW1 + e]);
  }
  #pragma unroll
  for (int c=0;c<8;c++){
    const int e = c*2048 + tid*8, row = e>>7, col = e&127;
    gload16(W2k + (size_t)row*128 + (col ^ ((row&7)<<3)), &lds[2*JW1 + e]);
  }
  asm volatile("s_waitcnt vmcnt(8)" ::: "memory");
  __builtin_amdgcn_s_barrier();
  __builtin_amdgcn_sched_barrier(0);

  f32x4 acc[4][4];
  #pragma unroll
  for (int mi=0;mi<4;mi++)
    #pragma unroll
    for (int ni=0;ni<4;ni++){ f32x4 zv={0.f,0.f,0.f,0.f}; acc[mi][ni]=zv; }
  #pragma unroll
  for (int k0=0; k0<DIN; k0+=32){
    bf16x8 aj[4], wh[4];
    #pragma unroll
    for (int mi=0;mi<4;mi++)
      aj[mi] = *(const bf16x8*)&lds[(wm+mi*16+rl)*DIN + ((k0+ksb*8) ^ xr)];
    #pragma unroll
    for (int ni=0;ni<4;ni++)
      wh[ni] = *(const bf16x8*)&lds[JW1 + (wn+ni*16+rl)*DIN + ((k0+ksb*8) ^ xr)];
    #pragma unroll
    for (int ni=0;ni<4;ni++)
      #pragma unroll
      for (int mi=0;mi<4;mi++)
        acc[mi][ni] = __builtin_amdgcn_mfma_f32_16x16x32_bf16(aj[mi], wh[ni], acc[mi][ni], 0,0,0);
  }
  __syncthreads();

  float bh[4];
  #pragma unroll
  for (int ni=0;ni<4;ni++) bh[ni] = b1g[k*128 + wn + ni*16 + rl];
  #pragma unroll
  for (int ni=0;ni<4;ni++){
    const int h = wn + ni*16 + rl;
    #pragma unroll
    for (int mi=0;mi<4;mi++){
      #pragma unroll
      for (int r=0;r<4;r++){
        const int j = wm + mi*16 + ksb*4 + r;
        lds[j*128 + (h ^ ((j&7)<<3))] = f2bf(fmaxf(acc[mi][ni][r] + bh[ni], 0.f));
      }
    }
  }
  __syncthreads();

  f32x4 acc2[4][4];
  #pragma unroll
  for (int mi=0;mi<4;mi++)
    #pragma unroll
    for (int ni=0;ni<4;ni++){ f32x4 zv={0.f,0.f,0.f,0.f}; acc2[mi][ni]=zv; }
  #pragma unroll
  for (int k0=0; k0<128; k0+=32){
    bf16x8 ao[4], mj[4];
    #pragma unroll
    for (int mi=0;mi<4;mi++)
      ao[mi] = *(const bf16x8*)&lds[2*JW1 + (wm+mi*16+rl)*128 + ((k0+ksb*8) ^ xr)];
    #pragma unroll
    for (int ni=0;ni<4;ni++)
      mj[ni] = *(const bf16x8*)&lds[(wn+ni*16+rl)*128 + ((k0+ksb*8) ^ xr)];
    #pragma unroll
    for (int ni=0;ni<4;ni++)
      #pragma unroll
      for (int mi=0;mi<4;mi++)
        acc2[mi][ni] = __builtin_amdgcn_mfma_f32_16x16x32_bf16(ao[mi], mj[ni], acc2[mi][ni], 0,0,0);
  }

  const float ws = wsl[k];
  #pragma unroll
  for (int mi=0;mi<4;mi++){
    #pragma unroll
    for (int r=0;r<4;r++){
      const int o = wm + mi*16 + ksb*4 + r;
      const float bo = b2g[k*128 + o];
      #pragma unroll
      for (int ni=0;ni<4;ni++){
        const int j = wn + ni*16 + rl;
        M2T[(size_t)(b*128 + o)*3072 + k*1024 + jt*128 + j] = f2bf((acc2[mi][ni][r] + bo) * ws);
      }
    }
  }
}

// ---------------- pool combine + head ----------------
__global__ void pool_combine(const float* __restrict__ Pp, float* __restrict__ pooled){
  const int row = blockIdx.x*256 + threadIdx.x;   // 8192 rows
  float s = 0.f;
  #pragma unroll
  for (int i=0;i<16;i++) s += Pp[(size_t)i*8192 + row];
  pooled[row] = s * (1.f/1024.f);
}

__global__ void head_kernel(const float* __restrict__ pooled, const float* __restrict__ Wc1,
                            const float* __restrict__ bc1, const float* __restrict__ alpha,
                            const float* __restrict__ Wc2, const float* __restrict__ bc2,
                            float* __restrict__ out){
  const int b = blockIdx.x, h = threadIdx.x;
  __shared__ float p[128], zz[128];
  p[h] = pooled[b*128+h];
  __syncthreads();
  float acc = bc1[h];
  for (int d=0; d<128; d++) acc = fmaf(p[d], Wc1[d*128+h], acc);
  zz[h] = acc>0.f ? acc : alpha[h]*acc;    // PReLU
  __syncthreads();
  if (h<4){
    float a = bc2[h];
    for (int q=0;q<128;q++) a = fmaf(zz[q], Wc2[q*4+h], a);
    out[b*4+h]=a;
  }
}

// ---------------- launcher ----------------
extern "C" void kernel_launch(void* const* d_in, const int* in_sizes, int n_in,
                              void* d_out, int out_size, void* d_ws, size_t ws_size,
                              hipStream_t stream)
{
  const float* x     = (const float*)d_in[0];
  const float* U     = (const float*)d_in[1];
  const float* w1_0  = (const float*)d_in[2];
  const float* b1_0  = (const float*)d_in[3];
  const float* w2_0  = (const float*)d_in[4];
  const float* b2_0  = (const float*)d_in[5];
  const float* w1_r  = (const float*)d_in[6];
  const float* b1_r  = (const float*)d_in[7];
  const float* w2_r  = (const float*)d_in[8];
  const float* b2_r  = (const float*)d_in[9];
  const float* bw    = (const float*)d_in[10];
  const float* Wc1   = (const float*)d_in[11];
  const float* bc1   = (const float*)d_in[12];
  const float* alpha = (const float*)d_in[13];
  const float* Wc2   = (const float*)d_in[14];
  const float* bc2   = (const float*)d_in[15];
  float* out = (float*)d_out;

  char* wsp = (char*)d_ws;
  size_t off = 0;
  auto alloc = [&](size_t bytes) -> void* {
    void* p = wsp + off;
    off = (off + bytes + 255) & ~(size_t)255;
    return p;
  };
  u16* UTcat = (u16*)alloc(6291456);     // [3][1024][1024]
  u16* Ucat  = (u16*)alloc(6291456);     // [1024][3072]
  u16* W1T0  = (u16*)alloc(49152);
  u16* W2T0  = (u16*)alloc(98304);
  u16* W1Tr  = (u16*)alloc(196608);
  u16* W2Tr  = (u16*)alloc(196608);
  float* wsb = (float*)alloc(256);
  u16* HT    = (u16*)alloc(16777216);    // [8192][1024]
  u16* AGG   = (u16*)alloc(50331648);    // AGG2 (l0 only)
  u16* M2T   = (u16*)alloc(50331648);    // [8192][3072]
  float* partials = (float*)alloc(524288);  // [16][8192]
  float* pooled   = (float*)alloc(32768);
  if (off > ws_size) return;

  prep_weights<<<1056, 256, 0, stream>>>(w1_0,w2_0,w1_r,w2_r,bw,
      W1T0,W2T0,W1Tr,W2Tr,wsb);
  prep_U<<<dim3(32,32,3), dim3(32,8), 0, stream>>>(U, UTcat, Ucat);
  prep_x<<<dim3(2,32,64), dim3(32,8), 0, stream>>>(x, HT);

  for (int l=0; l<3; l++){
    const float* b1 = l ? b1_r + (l-1)*384 : b1_0;
    const float* b2 = l ? b2_r + (l-1)*384 : b2_0;

    if (l == 0){
      // AGG2[((k*64+b)*1024+j)][d] then separate fused MLP (Din=64)
      gemm_big<false,6,false><<<dim3(32, 4, 3), 512, 0, stream>>>(
          UTcat, HT, AGG, nullptr, 4096, 1024, 1048576L, 0);
      fused_mlp<64><<<dim3(8, 1, 192), 256, 0, stream>>>(
          AGG, W1T0, W2T0, b1, b2, wsb, M2T);
    } else {
      // AGG + full MLP fused (80KB LDS, 2 blocks/CU): writes M2T directly
      gemm_agg_mlp<<<dim3(64, 4, 3), 512, 0, stream>>>(
          UTcat, HT,
          W1Tr + (size_t)(l-1)*3*16384, W2Tr + (size_t)(l-1)*3*16384,
          b1, b2, wsb + l*3, M2T);
    }
    // HT = relu(M2T @ Ucat); l2 pools in-register instead of writing HT
    if (l < 2)
      gemm_big<true,0,false><<<dim3(8, 32, 1), 512, 0, stream>>>(
          M2T, Ucat, HT, nullptr, 1024, 3072, 0L, 0);
    else
      gemm_big<true,0,true><<<dim3(8, 32, 1), 512, 0, stream>>>(
          M2T, Ucat, nullptr, partials, 1024, 3072, 0L, 0);
  }
  pool_combine<<<32, 256, 0, stream>>>(partials, pooled);
  head_kernel<<<64, 128, 0, stream>>>(pooled, Wc1, bc1, alpha, Wc2, bc2, out);
}